// Round 10
// baseline (180.845 us; speedup 1.0000x reference)
//
#include <hip/hip_runtime.h>

#define NSEQ 4096
#define CHN 256

typedef __attribute__((ext_vector_type(8))) short short8;
typedef __attribute__((ext_vector_type(4))) float f32x4;
typedef __attribute__((ext_vector_type(4))) int i32x4;
typedef __attribute__((ext_vector_type(4))) unsigned short us4;
typedef unsigned short u16;

// fp32 -> bf16 round-to-nearest-even (off the hot path)
__device__ __forceinline__ u16 f2b(float f) {
  unsigned u = __builtin_bit_cast(unsigned, f);
  unsigned r = (u + 0x7fffu + ((u >> 16) & 1u)) >> 16;
  return (u16)r;
}
__device__ __forceinline__ float b2f(u16 h) {
  unsigned u = ((unsigned)h) << 16;
  return __builtin_bit_cast(float, u);
}

// raw v_exp_f32 (2^x); ocml exp2f carries ~8 guard instrs we don't need (|x|<64)
#if __has_builtin(__builtin_amdgcn_exp2f)
#define FEXP2(x) __builtin_amdgcn_exp2f(x)
#else
__device__ __forceinline__ float fexp2_asm(float x) {
  float r;
  asm("v_exp_f32 %0, %1\n\ts_nop 0" : "=v"(r) : "v"(x));  // s_nop covers trans->VALU hazard
  return r;
}
#define FEXP2(x) fexp2_asm(x)
#endif

// ws layout in u16 elements.
// Kf: [B][128 ci][4 part][64 lane][8]  part: 0=hi/frag0 1=hi/frag1 2=lo/frag0 3=lo/frag1
// Vf: [B][128 ci][8 vt][64 lane][8]
// Wqkf: [2 hl][2 slice][8 kc][2 ot][64][8]   Wgf: [2 half][8 kc][4 oi][64][8]
// Wof: [16 mt][4 kc][64][8]
#define QH_OFF   0u
#define QL_OFF   524288u
#define KF_OFF   1048576u
#define VF_OFF   2097152u
#define WQKF_OFF 4194304u
#define WGF_OFF  4227072u
#define WOF_OFF  4259840u

// ---------------- kernel 0: weight prep -> fragment layouts (frozen from r9) ----------------
__global__ __launch_bounds__(256) void prep_weights(
    const float* __restrict__ Wt, const float* __restrict__ Wp,
    const float* __restrict__ Wg, const float* __restrict__ Wo,
    u16* __restrict__ Wqkf, u16* __restrict__ Wgf, u16* __restrict__ Wof) {
  int gid = blockIdx.x * 256 + threadIdx.x;
  if (gid < 4096) {
    int row = gid >> 6;
    int c0 = (gid & 63) * 4;
    const float* src;
    float scale = 1.0f;
    if (row < 32) { src = Wt + row * 256; scale = 1.44269504088896340736f; }
    else          { src = Wp + (row - 32) * 256; }
    float4 v = *(const float4*)(src + c0);
    float w0 = v.x * scale, w1 = v.y * scale, w2 = v.z * scale, w3 = v.w * scale;
    us4 hi = { f2b(w0), f2b(w1), f2b(w2), f2b(w3) };
    us4 lo = { f2b(w0 - b2f(hi[0])), f2b(w1 - b2f(hi[1])),
               f2b(w2 - b2f(hi[2])), f2b(w3 - b2f(hi[3])) };
    int slice = row >> 5, ot = (row >> 4) & 1, l15t = row & 15;
    int kc = c0 >> 5, quad_t = (c0 & 31) >> 3, j0 = c0 & 7;
    size_t base = ((size_t)(((slice * 8 + kc) * 2 + ot) * 64 + quad_t * 16 + l15t)) * 8 + j0;
    *(us4*)(Wqkf + base) = hi;
    *(us4*)(Wqkf + base + 16384) = lo;
  } else if (gid < 12288) {
    int t = gid - 4096;
    int row = t >> 6;
    int c0 = (t & 63) * 4;
    float4 v = *(const float4*)(Wg + row * 256 + c0);
    us4 o = { f2b(v.x), f2b(v.y), f2b(v.z), f2b(v.w) };
    int half = row >> 6, oi = (row >> 4) & 3, l15t = row & 15;
    int kc = c0 >> 5, quad_t = (c0 & 31) >> 3, j0 = c0 & 7;
    size_t base = ((size_t)(((half * 8 + kc) * 4 + oi) * 64 + quad_t * 16 + l15t)) * 8 + j0;
    *(us4*)(Wgf + base) = o;
  } else {
    int t = gid - 12288;
    int g = t * 4;
    int oc = g >> 7, c0 = g & 127;
    float4 v = *(const float4*)(Wo + g);
    us4 o = { f2b(v.x), f2b(v.y), f2b(v.z), f2b(v.w) };
    int mt = oc >> 4, l15t = oc & 15;
    int kc = c0 >> 5, quad_t = (c0 & 31) >> 3, j0 = c0 & 7;
    size_t base = ((size_t)((mt * 4 + kc) * 64 + quad_t * 16 + l15t)) * 8 + j0;
    *(us4*)(Wof + base) = o;
  }
}

// ---------------- kernel 1: QKV projection (r9, frozen) ----------------
// proj ledger: r9 4-block=29us, v11 fused=34, v12 2-block=30, v13 LDS-staged=30.7
// -> access pattern / TLP / conversion-dedup all null; frozen at r9.
__global__ __launch_bounds__(256, 4) void proj_qkv(
    const float* __restrict__ x,
    const u16* __restrict__ Wqkf, const u16* __restrict__ Wgf,
    u16* __restrict__ QbH, u16* __restrict__ QbL,
    u16* __restrict__ Kf, u16* __restrict__ Vf) {
  int tid = threadIdx.x;
  int wave = tid >> 6, lane = tid & 63;
  int l15 = lane & 15, quad = lane >> 4;
  int slice = blockIdx.x >> 8;
  int tb = blockIdx.x & 255;
  int b = tb >> 6;
  int n0 = (tb & 63) * 64;
  int pos = n0 + wave * 16 + l15;
  const float* xb = x + (size_t)b * CHN * NSEQ + pos;
  int nbase = n0 + wave * 16 + quad * 4;

  if (slice < 2) {
    f32x4 acc[2];
    acc[0] = (f32x4){0.f, 0.f, 0.f, 0.f};
    acc[1] = (f32x4){0.f, 0.f, 0.f, 0.f};
#pragma unroll
    for (int kc = 0; kc < 8; kc++) {
      short8 ahi, alo;
#pragma unroll
      for (int j = 0; j < 8; j++) {
        float xv = xb[(size_t)(kc * 32 + quad * 8 + j) * NSEQ];
        u16 hi = f2b(xv);
        ahi[j] = (short)hi;
        alo[j] = (short)f2b(xv - b2f(hi));
      }
#pragma unroll
      for (int ot = 0; ot < 2; ot++) {
        size_t off = ((size_t)((slice * 8 + kc) * 2 + ot)) * 512 + lane * 8;
        short8 bh = *(const short8*)(Wqkf + off);
        short8 bl = *(const short8*)(Wqkf + off + 16384);
        acc[ot] = __builtin_amdgcn_mfma_f32_16x16x32_bf16(alo, bh, acc[ot], 0, 0, 0);
        acc[ot] = __builtin_amdgcn_mfma_f32_16x16x32_bf16(ahi, bl, acc[ot], 0, 0, 0);
        acc[ot] = __builtin_amdgcn_mfma_f32_16x16x32_bf16(ahi, bh, acc[ot], 0, 0, 0);
      }
    }
#pragma unroll
    for (int ot = 0; ot < 2; ot++) {
#pragma unroll
      for (int r = 0; r < 4; r++) {
        float v = acc[ot][r];
        u16 hi = f2b(v);
        u16 lo = f2b(v - b2f(hi));
        if (slice == 0) {
          size_t nrow = (size_t)(b * NSEQ + nbase + r) * 32 + ot * 16 + l15;
          QbH[nrow] = hi; QbL[nrow] = lo;
        } else {
          int key = nbase + r;
          int oc = ot * 16 + l15;
          int ci = key >> 5, k32 = key & 31;
          int frag = (k32 >> 2) & 1;
          int rkv = k32 - 4 * frag;
          int l15t = ((rkv >> 3) << 2) | (rkv & 3);
          int lane_t = ((oc >> 3) << 4) + l15t;
          size_t base = (size_t)b * 262144 + (size_t)(ci * 4 + frag) * 512 + lane_t * 8 + (oc & 7);
          Kf[base] = hi;
          Kf[base + 1024] = lo;
        }
      }
    }
  } else {
    f32x4 acc[4];
#pragma unroll
    for (int oi = 0; oi < 4; oi++) acc[oi] = (f32x4){0.f, 0.f, 0.f, 0.f};
#pragma unroll
    for (int kc = 0; kc < 8; kc++) {
      short8 ahi;
#pragma unroll
      for (int j = 0; j < 8; j++)
        ahi[j] = (short)f2b(xb[(size_t)(kc * 32 + quad * 8 + j) * NSEQ]);
#pragma unroll
      for (int oi = 0; oi < 4; oi++) {
        short8 bg = *(const short8*)(Wgf + ((size_t)(((slice - 2) * 8 + kc) * 4 + oi)) * 512 + lane * 8);
        acc[oi] = __builtin_amdgcn_mfma_f32_16x16x32_bf16(ahi, bg, acc[oi], 0, 0, 0);
      }
    }
#pragma unroll
    for (int oi = 0; oi < 4; oi++) {
      int ch = (slice - 2) * 64 + oi * 16 + l15;
      int vt = ((ch >> 5) << 1) | ((ch >> 2) & 1);
      int rkv = (ch & 31) - ((ch >> 2) & 1) * 4;
      int l15t = ((rkv >> 3) << 2) | (rkv & 3);
      int ci = nbase >> 5, mc = nbase & 31;
      int lane_t = ((mc >> 3) << 4) + l15t;
      us4 pk = { f2b(acc[oi][0]), f2b(acc[oi][1]), f2b(acc[oi][2]), f2b(acc[oi][3]) };
      size_t addr = (size_t)b * 524288 + (size_t)(ci * 8 + vt) * 512 + lane_t * 8 + (mc & 7);
      *(us4*)(Vf + addr) = pk;
    }
  }
}

// ---------------- kernel 2: fused flash attention + Wo + epilogue (v16) ----------------
// v15 post-mortem: load lambdas writing buffers through pointer params defeated
// SROA -> buffers went to scratch (VGPR capped 128, WRITE_SIZE 240MB, dur 102us).
// v16 = the same depth-2 prefetch experiment written v8-style: three NAMED K/V
// buffer sets, fully INLINE unrolled loads, pointer-increment addressing. Only
// the proven compute() lambda remains. ~155 arch + 64 AGPR ~= 220 unified <= 256
// at the unchanged 2 waves/SIMD. Numerics/combine/epilogue byte-identical to v8.
// Loads cover chunks 0..31 exactly (no over-read).
__global__ __launch_bounds__(512, 1) void flash_attn(
    const u16* __restrict__ QbH, const u16* __restrict__ QbL,
    const u16* __restrict__ Kf, const u16* __restrict__ Vf,
    const u16* __restrict__ Wof,
    const float* __restrict__ x, const float* __restrict__ gammap,
    float* __restrict__ out) {
  __shared__ alignas(16) char smem[67584];
  f32x4 (*CombA)[16][64] = (f32x4(*)[16][64])smem;
  f32x4 (*CombB)[16][64] = (f32x4(*)[16][64])(smem + 32768);
  float (*CombLA)[2][64] = (float(*)[2][64])(smem + 65536);
  float (*CombLB)[2][64] = (float(*)[2][64])(smem + 66560);
  u16* BC = (u16*)smem;   // [4 nqt][64 lanes][40] aliases CombA post-barrier

  int tid = threadIdx.x;
  int wave = tid >> 6, lane = tid & 63;
  int l15 = lane & 15, quad = lane >> 4;
  int sp = wave >> 1, rg = wave & 1;
  int b = blockIdx.x & 3;
  int tile = blockIdx.x >> 2;
  int n0 = tile * 64;
  int nqb = n0 + rg * 32;

  short8 qh[2], ql[2];
#pragma unroll
  for (int nt = 0; nt < 2; nt++) {
    size_t qoff = (size_t)(b * NSEQ + nqb + nt * 16 + l15) * 32 + quad * 8;
    qh[nt] = *(const short8*)(QbH + qoff);
    ql[nt] = *(const short8*)(QbL + qoff);
  }
  const u16* Kp = Kf + (size_t)b * 262144 + (size_t)sp * 32 * 2048 + lane * 8;
  const u16* Vp = Vf + (size_t)b * 524288 + (size_t)sp * 32 * 4096 + lane * 8;

  f32x4 acc[2][8];
#pragma unroll
  for (int nt = 0; nt < 2; nt++)
#pragma unroll
    for (int vt = 0; vt < 8; vt++) acc[nt][vt] = (f32x4){0.f, 0.f, 0.f, 0.f};
  float lsum[2] = {0.f, 0.f};

  short8 kA[4], kB[4], kC[4], vA[8], vB[8], vC[8];

  // one chunk: QK^T (hi/lo, small terms first) -> exp2 -> truncation-pack -> PV
  auto compute = [&](const short8* k, const short8* v) {
#pragma unroll
    for (int nt = 0; nt < 2; nt++) {
      f32x4 z = (f32x4){0.f, 0.f, 0.f, 0.f};
      __builtin_amdgcn_s_setprio(1);
      f32x4 s0 = __builtin_amdgcn_mfma_f32_16x16x32_bf16(k[2], qh[nt], z, 0, 0, 0);
      s0 = __builtin_amdgcn_mfma_f32_16x16x32_bf16(k[0], ql[nt], s0, 0, 0, 0);
      s0 = __builtin_amdgcn_mfma_f32_16x16x32_bf16(k[0], qh[nt], s0, 0, 0, 0);
      f32x4 s1 = __builtin_amdgcn_mfma_f32_16x16x32_bf16(k[3], qh[nt], z, 0, 0, 0);
      s1 = __builtin_amdgcn_mfma_f32_16x16x32_bf16(k[1], ql[nt], s1, 0, 0, 0);
      s1 = __builtin_amdgcn_mfma_f32_16x16x32_bf16(k[1], qh[nt], s1, 0, 0, 0);
      __builtin_amdgcn_s_setprio(0);

      float e0 = FEXP2(s0[0]), e1 = FEXP2(s0[1]), e2 = FEXP2(s0[2]), e3 = FEXP2(s0[3]);
      float e4 = FEXP2(s1[0]), e5 = FEXP2(s1[1]), e6 = FEXP2(s1[2]), e7 = FEXP2(s1[3]);
      lsum[nt] += ((e0 + e1) + (e2 + e3)) + ((e4 + e5) + (e6 + e7));
      i32x4 pi;
      pi[0] = (int)((__builtin_bit_cast(unsigned, e0) >> 16) | (__builtin_bit_cast(unsigned, e1) & 0xffff0000u));
      pi[1] = (int)((__builtin_bit_cast(unsigned, e2) >> 16) | (__builtin_bit_cast(unsigned, e3) & 0xffff0000u));
      pi[2] = (int)((__builtin_bit_cast(unsigned, e4) >> 16) | (__builtin_bit_cast(unsigned, e5) & 0xffff0000u));
      pi[3] = (int)((__builtin_bit_cast(unsigned, e6) >> 16) | (__builtin_bit_cast(unsigned, e7) & 0xffff0000u));
      short8 pp = __builtin_bit_cast(short8, pi);
      __builtin_amdgcn_s_setprio(1);
#pragma unroll
      for (int vt = 0; vt < 8; vt++)
        acc[nt][vt] = __builtin_amdgcn_mfma_f32_16x16x32_bf16(v[vt], pp, acc[nt][vt], 0, 0, 0);
      __builtin_amdgcn_s_setprio(0);
    }
  };

  // ---- depth-2 software pipeline over 32 chunks, all loads inline ----
  // prologue: chunks 0 (A), 1 (B)
#pragma unroll
  for (int p = 0; p < 4; p++) kA[p] = *(const short8*)(Kp + p * 512);
#pragma unroll
  for (int vt = 0; vt < 8; vt++) vA[vt] = *(const short8*)(Vp + vt * 512);
  Kp += 2048; Vp += 4096;
#pragma unroll
  for (int p = 0; p < 4; p++) kB[p] = *(const short8*)(Kp + p * 512);
#pragma unroll
  for (int vt = 0; vt < 8; vt++) vB[vt] = *(const short8*)(Vp + vt * 512);

  for (int i = 0; i < 10; i++) {
    Kp += 2048; Vp += 4096;       // chunk 3i+2 -> C
#pragma unroll
    for (int p = 0; p < 4; p++) kC[p] = *(const short8*)(Kp + p * 512);
#pragma unroll
    for (int vt = 0; vt < 8; vt++) vC[vt] = *(const short8*)(Vp + vt * 512);
    compute(kA, vA);              // chunk 3i

    Kp += 2048; Vp += 4096;       // chunk 3i+3 -> A
#pragma unroll
    for (int p = 0; p < 4; p++) kA[p] = *(const short8*)(Kp + p * 512);
#pragma unroll
    for (int vt = 0; vt < 8; vt++) vA[vt] = *(const short8*)(Vp + vt * 512);
    compute(kB, vB);              // chunk 3i+1

    Kp += 2048; Vp += 4096;       // chunk 3i+4 -> B
#pragma unroll
    for (int p = 0; p < 4; p++) kB[p] = *(const short8*)(Kp + p * 512);
#pragma unroll
    for (int vt = 0; vt < 8; vt++) vB[vt] = *(const short8*)(Vp + vt * 512);
    compute(kC, vC);              // chunk 3i+2
  }
  compute(kA, vA);                // chunk 30
  compute(kB, vB);                // chunk 31

  // ---- split-K tree combine: (sp2->sp0, sp3->sp1), then sp1->sp0 ----
  if (sp == 2) {
#pragma unroll
    for (int nt = 0; nt < 2; nt++) {
#pragma unroll
      for (int vt = 0; vt < 8; vt++) CombA[rg][nt * 8 + vt][lane] = acc[nt][vt];
      CombLA[rg][nt][lane] = lsum[nt];
    }
  } else if (sp == 3) {
#pragma unroll
    for (int nt = 0; nt < 2; nt++) {
#pragma unroll
      for (int vt = 0; vt < 8; vt++) CombB[rg][nt * 8 + vt][lane] = acc[nt][vt];
      CombLB[rg][nt][lane] = lsum[nt];
    }
  }
  __syncthreads();
  if (sp == 0) {
#pragma unroll
    for (int nt = 0; nt < 2; nt++) {
#pragma unroll
      for (int vt = 0; vt < 8; vt++) acc[nt][vt] += CombA[rg][nt * 8 + vt][lane];
      lsum[nt] += CombLA[rg][nt][lane];
    }
  } else if (sp == 1) {
#pragma unroll
    for (int nt = 0; nt < 2; nt++) {
#pragma unroll
      for (int vt = 0; vt < 8; vt++) acc[nt][vt] += CombB[rg][nt * 8 + vt][lane];
      lsum[nt] += CombLB[rg][nt][lane];
    }
  }
  __syncthreads();
  if (sp == 1) {
#pragma unroll
    for (int nt = 0; nt < 2; nt++) {
#pragma unroll
      for (int vt = 0; vt < 8; vt++) CombA[rg][nt * 8 + vt][lane] = acc[nt][vt];
      CombLA[rg][nt][lane] = lsum[nt];
    }
  }
  __syncthreads();
  if (sp == 0) {
#pragma unroll
    for (int nt = 0; nt < 2; nt++) {
#pragma unroll
      for (int vt = 0; vt < 8; vt++) acc[nt][vt] += CombA[rg][nt * 8 + vt][lane];
      lsum[nt] += CombLA[rg][nt][lane];
    }
#pragma unroll
    for (int nt = 0; nt < 2; nt++) {
      lsum[nt] += __shfl_xor(lsum[nt], 16);
      lsum[nt] += __shfl_xor(lsum[nt], 32);
      float rinv = 1.0f / lsum[nt];
      int nqt = rg * 2 + nt;
#pragma unroll
      for (int kc = 0; kc < 4; kc++) {
        short8 t;
#pragma unroll
        for (int r = 0; r < 4; r++) {
          t[r]     = (short)f2b(acc[nt][2 * kc][r] * rinv);
          t[r + 4] = (short)f2b(acc[nt][2 * kc + 1][r] * rinv);
        }
        *(short8*)&BC[(size_t)(nqt * 64 + lane) * 40 + kc * 8] = t;
      }
    }
  }
  __syncthreads();

  // ---- Wo GEMM + epilogue: wave w -> oc-tiles 2w, 2w+1 ----
  short8 bfr[4][4];
#pragma unroll
  for (int nqt = 0; nqt < 4; nqt++)
#pragma unroll
    for (int kc = 0; kc < 4; kc++)
      bfr[nqt][kc] = *(const short8*)&BC[(size_t)(nqt * 64 + lane) * 40 + kc * 8];

  float gamma = *gammap;
#pragma unroll
  for (int mti = 0; mti < 2; mti++) {
    int mt = wave * 2 + mti;
    short8 wf[4];
#pragma unroll
    for (int kc = 0; kc < 4; kc++)
      wf[kc] = *(const short8*)(Wof + (size_t)(mt * 4 + kc) * 512 + lane * 8);
#pragma unroll
    for (int nqt = 0; nqt < 4; nqt++) {
      f32x4 oacc = (f32x4){0.f, 0.f, 0.f, 0.f};
#pragma unroll
      for (int kc = 0; kc < 4; kc++)
        oacc = __builtin_amdgcn_mfma_f32_16x16x32_bf16(wf[kc], bfr[nqt][kc], oacc, 0, 0, 0);
#pragma unroll
      for (int r = 0; r < 4; r++) {
        int oc = mt * 16 + quad * 4 + r;
        size_t idx = ((size_t)b * CHN + oc) * NSEQ + n0 + nqt * 16 + l15;
        out[idx] = gamma * oacc[r] + x[idx];
      }
    }
  }
}

extern "C" void kernel_launch(void* const* d_in, const int* in_sizes, int n_in,
                              void* d_out, int out_size, void* d_ws, size_t ws_size,
                              hipStream_t stream) {
  const float* x  = (const float*)d_in[0];
  const float* Wt = (const float*)d_in[1];
  const float* Wp = (const float*)d_in[2];
  const float* Wg = (const float*)d_in[3];
  const float* Wo = (const float*)d_in[4];
  const float* gm = (const float*)d_in[5];
  float* out = (float*)d_out;
  u16* ws = (u16*)d_ws;
  u16* QbH  = ws + QH_OFF;
  u16* QbL  = ws + QL_OFF;
  u16* Kf   = ws + KF_OFF;
  u16* Vf   = ws + VF_OFF;
  u16* Wqkf = ws + WQKF_OFF;
  u16* Wgf  = ws + WGF_OFF;
  u16* Wof  = ws + WOF_OFF;

  prep_weights<<<80, 256, 0, stream>>>(Wt, Wp, Wg, Wo, Wqkf, Wgf, Wof);
  proj_qkv<<<1024, 256, 0, stream>>>(x, Wqkf, Wgf, QbH, QbL, Kf, Vf);
  flash_attn<<<256, 512, 0, stream>>>(QbH, QbL, Kf, Vf, Wof, x, gm, out);
}

// Round 11
// 118.248 us; speedup vs baseline: 1.5294x; 1.5294x over previous
//
#include <hip/hip_runtime.h>

#define NSEQ 4096
#define CHN 256

typedef __attribute__((ext_vector_type(8))) short short8;
typedef __attribute__((ext_vector_type(4))) float f32x4;
typedef __attribute__((ext_vector_type(4))) int i32x4;
typedef __attribute__((ext_vector_type(4))) unsigned short us4;
typedef unsigned short u16;

// fp32 -> bf16 round-to-nearest-even (off the hot path)
__device__ __forceinline__ u16 f2b(float f) {
  unsigned u = __builtin_bit_cast(unsigned, f);
  unsigned r = (u + 0x7fffu + ((u >> 16) & 1u)) >> 16;
  return (u16)r;
}
__device__ __forceinline__ float b2f(u16 h) {
  unsigned u = ((unsigned)h) << 16;
  return __builtin_bit_cast(float, u);
}

// raw v_exp_f32 (2^x); ocml exp2f carries ~8 guard instrs we don't need (|x|<64)
#if __has_builtin(__builtin_amdgcn_exp2f)
#define FEXP2(x) __builtin_amdgcn_exp2f(x)
#else
__device__ __forceinline__ float fexp2_asm(float x) {
  float r;
  asm("v_exp_f32 %0, %1\n\ts_nop 0" : "=v"(r) : "v"(x));  // s_nop covers trans->VALU hazard
  return r;
}
#define FEXP2(x) fexp2_asm(x)
#endif

// ws layout in u16 elements.
// Kf: [B][128 ci][4 part][64 lane][8]  part: 0=hi/frag0 1=hi/frag1 2=lo/frag0 3=lo/frag1
// Vf: [B][128 ci][8 vt][64 lane][8]
// Wqkf: [2 hl][2 slice][8 kc][2 ot][64][8]   Wgf: [2 half][8 kc][4 oi][64][8]
// Wof: [16 mt][4 kc][64][8]
#define QH_OFF   0u
#define QL_OFF   524288u
#define KF_OFF   1048576u
#define VF_OFF   2097152u
#define WQKF_OFF 4194304u
#define WGF_OFF  4227072u
#define WOF_OFF  4259840u

// ---------------- kernel 0: weight prep -> fragment layouts (frozen from r9) ----------------
__global__ __launch_bounds__(256) void prep_weights(
    const float* __restrict__ Wt, const float* __restrict__ Wp,
    const float* __restrict__ Wg, const float* __restrict__ Wo,
    u16* __restrict__ Wqkf, u16* __restrict__ Wgf, u16* __restrict__ Wof) {
  int gid = blockIdx.x * 256 + threadIdx.x;
  if (gid < 4096) {
    int row = gid >> 6;
    int c0 = (gid & 63) * 4;
    const float* src;
    float scale = 1.0f;
    if (row < 32) { src = Wt + row * 256; scale = 1.44269504088896340736f; }
    else          { src = Wp + (row - 32) * 256; }
    float4 v = *(const float4*)(src + c0);
    float w0 = v.x * scale, w1 = v.y * scale, w2 = v.z * scale, w3 = v.w * scale;
    us4 hi = { f2b(w0), f2b(w1), f2b(w2), f2b(w3) };
    us4 lo = { f2b(w0 - b2f(hi[0])), f2b(w1 - b2f(hi[1])),
               f2b(w2 - b2f(hi[2])), f2b(w3 - b2f(hi[3])) };
    int slice = row >> 5, ot = (row >> 4) & 1, l15t = row & 15;
    int kc = c0 >> 5, quad_t = (c0 & 31) >> 3, j0 = c0 & 7;
    size_t base = ((size_t)(((slice * 8 + kc) * 2 + ot) * 64 + quad_t * 16 + l15t)) * 8 + j0;
    *(us4*)(Wqkf + base) = hi;
    *(us4*)(Wqkf + base + 16384) = lo;
  } else if (gid < 12288) {
    int t = gid - 4096;
    int row = t >> 6;
    int c0 = (t & 63) * 4;
    float4 v = *(const float4*)(Wg + row * 256 + c0);
    us4 o = { f2b(v.x), f2b(v.y), f2b(v.z), f2b(v.w) };
    int half = row >> 6, oi = (row >> 4) & 3, l15t = row & 15;
    int kc = c0 >> 5, quad_t = (c0 & 31) >> 3, j0 = c0 & 7;
    size_t base = ((size_t)(((half * 8 + kc) * 4 + oi) * 64 + quad_t * 16 + l15t)) * 8 + j0;
    *(us4*)(Wgf + base) = o;
  } else {
    int t = gid - 12288;
    int g = t * 4;
    int oc = g >> 7, c0 = g & 127;
    float4 v = *(const float4*)(Wo + g);
    us4 o = { f2b(v.x), f2b(v.y), f2b(v.z), f2b(v.w) };
    int mt = oc >> 4, l15t = oc & 15;
    int kc = c0 >> 5, quad_t = (c0 & 31) >> 3, j0 = c0 & 7;
    size_t base = ((size_t)((mt * 4 + kc) * 64 + quad_t * 16 + l15t)) * 8 + j0;
    *(us4*)(Wof + base) = o;
  }
}

// ---------------- kernel 1: QKV projection (r9, frozen) ----------------
// proj ledger: r9 4-block=29us, v11 fused=34, v12 2-block=30, v13 LDS-staged=30.7
// -> access pattern / TLP / conversion-dedup all null; frozen at r9.
__global__ __launch_bounds__(256, 4) void proj_qkv(
    const float* __restrict__ x,
    const u16* __restrict__ Wqkf, const u16* __restrict__ Wgf,
    u16* __restrict__ QbH, u16* __restrict__ QbL,
    u16* __restrict__ Kf, u16* __restrict__ Vf) {
  int tid = threadIdx.x;
  int wave = tid >> 6, lane = tid & 63;
  int l15 = lane & 15, quad = lane >> 4;
  int slice = blockIdx.x >> 8;
  int tb = blockIdx.x & 255;
  int b = tb >> 6;
  int n0 = (tb & 63) * 64;
  int pos = n0 + wave * 16 + l15;
  const float* xb = x + (size_t)b * CHN * NSEQ + pos;
  int nbase = n0 + wave * 16 + quad * 4;

  if (slice < 2) {
    f32x4 acc[2];
    acc[0] = (f32x4){0.f, 0.f, 0.f, 0.f};
    acc[1] = (f32x4){0.f, 0.f, 0.f, 0.f};
#pragma unroll
    for (int kc = 0; kc < 8; kc++) {
      short8 ahi, alo;
#pragma unroll
      for (int j = 0; j < 8; j++) {
        float xv = xb[(size_t)(kc * 32 + quad * 8 + j) * NSEQ];
        u16 hi = f2b(xv);
        ahi[j] = (short)hi;
        alo[j] = (short)f2b(xv - b2f(hi));
      }
#pragma unroll
      for (int ot = 0; ot < 2; ot++) {
        size_t off = ((size_t)((slice * 8 + kc) * 2 + ot)) * 512 + lane * 8;
        short8 bh = *(const short8*)(Wqkf + off);
        short8 bl = *(const short8*)(Wqkf + off + 16384);
        acc[ot] = __builtin_amdgcn_mfma_f32_16x16x32_bf16(alo, bh, acc[ot], 0, 0, 0);
        acc[ot] = __builtin_amdgcn_mfma_f32_16x16x32_bf16(ahi, bl, acc[ot], 0, 0, 0);
        acc[ot] = __builtin_amdgcn_mfma_f32_16x16x32_bf16(ahi, bh, acc[ot], 0, 0, 0);
      }
    }
#pragma unroll
    for (int ot = 0; ot < 2; ot++) {
#pragma unroll
      for (int r = 0; r < 4; r++) {
        float v = acc[ot][r];
        u16 hi = f2b(v);
        u16 lo = f2b(v - b2f(hi));
        if (slice == 0) {
          size_t nrow = (size_t)(b * NSEQ + nbase + r) * 32 + ot * 16 + l15;
          QbH[nrow] = hi; QbL[nrow] = lo;
        } else {
          int key = nbase + r;
          int oc = ot * 16 + l15;
          int ci = key >> 5, k32 = key & 31;
          int frag = (k32 >> 2) & 1;
          int rkv = k32 - 4 * frag;
          int l15t = ((rkv >> 3) << 2) | (rkv & 3);
          int lane_t = ((oc >> 3) << 4) + l15t;
          size_t base = (size_t)b * 262144 + (size_t)(ci * 4 + frag) * 512 + lane_t * 8 + (oc & 7);
          Kf[base] = hi;
          Kf[base + 1024] = lo;
        }
      }
    }
  } else {
    f32x4 acc[4];
#pragma unroll
    for (int oi = 0; oi < 4; oi++) acc[oi] = (f32x4){0.f, 0.f, 0.f, 0.f};
#pragma unroll
    for (int kc = 0; kc < 8; kc++) {
      short8 ahi;
#pragma unroll
      for (int j = 0; j < 8; j++)
        ahi[j] = (short)f2b(xb[(size_t)(kc * 32 + quad * 8 + j) * NSEQ]);
#pragma unroll
      for (int oi = 0; oi < 4; oi++) {
        short8 bg = *(const short8*)(Wgf + ((size_t)(((slice - 2) * 8 + kc) * 4 + oi)) * 512 + lane * 8);
        acc[oi] = __builtin_amdgcn_mfma_f32_16x16x32_bf16(ahi, bg, acc[oi], 0, 0, 0);
      }
    }
#pragma unroll
    for (int oi = 0; oi < 4; oi++) {
      int ch = (slice - 2) * 64 + oi * 16 + l15;
      int vt = ((ch >> 5) << 1) | ((ch >> 2) & 1);
      int rkv = (ch & 31) - ((ch >> 2) & 1) * 4;
      int l15t = ((rkv >> 3) << 2) | (rkv & 3);
      int ci = nbase >> 5, mc = nbase & 31;
      int lane_t = ((mc >> 3) << 4) + l15t;
      us4 pk = { f2b(acc[oi][0]), f2b(acc[oi][1]), f2b(acc[oi][2]), f2b(acc[oi][3]) };
      size_t addr = (size_t)b * 524288 + (size_t)(ci * 8 + vt) * 512 + lane_t * 8 + (mc & 7);
      *(us4*)(Vf + addr) = pk;
    }
  }
}

// ---------------- kernel 2: fused flash attention + Wo + epilogue (v14, restored) ----------------
// v14 = v8 + T5 s_setprio around MFMA clusters. Best-measured config (119.7us total).
// Session ledger (why this is frozen): occupancy-up restructures (v9/v10) starve
// arch VGPRs -> MfmaUtil 28->18; depth-2 register prefetch (v15/v16) crosses the
// 128-VGPR cliff -> compiler spills (WRITE_SIZE 240MB, dur 103us) in BOTH source
// forms; proj variants null. The 108+64-reg 1-ahead dbuf at 2 waves/SIMD is the
// empirical optimum of this structure on this compiler.
__global__ __launch_bounds__(512, 1) void flash_attn(
    const u16* __restrict__ QbH, const u16* __restrict__ QbL,
    const u16* __restrict__ Kf, const u16* __restrict__ Vf,
    const u16* __restrict__ Wof,
    const float* __restrict__ x, const float* __restrict__ gammap,
    float* __restrict__ out) {
  __shared__ alignas(16) char smem[67584];
  f32x4 (*CombA)[16][64] = (f32x4(*)[16][64])smem;
  f32x4 (*CombB)[16][64] = (f32x4(*)[16][64])(smem + 32768);
  float (*CombLA)[2][64] = (float(*)[2][64])(smem + 65536);
  float (*CombLB)[2][64] = (float(*)[2][64])(smem + 66560);
  u16* BC = (u16*)smem;   // [4 nqt][64 lanes][40] aliases CombA post-barrier

  int tid = threadIdx.x;
  int wave = tid >> 6, lane = tid & 63;
  int l15 = lane & 15, quad = lane >> 4;
  int sp = wave >> 1, rg = wave & 1;
  int b = blockIdx.x & 3;
  int tile = blockIdx.x >> 2;
  int n0 = tile * 64;
  int nqb = n0 + rg * 32;

  short8 qh[2], ql[2];
#pragma unroll
  for (int nt = 0; nt < 2; nt++) {
    size_t qoff = (size_t)(b * NSEQ + nqb + nt * 16 + l15) * 32 + quad * 8;
    qh[nt] = *(const short8*)(QbH + qoff);
    ql[nt] = *(const short8*)(QbL + qoff);
  }
  const u16* Kp = Kf + (size_t)b * 262144 + (size_t)sp * 32 * 2048 + lane * 8;
  const u16* Vp = Vf + (size_t)b * 524288 + (size_t)sp * 32 * 4096 + lane * 8;

  f32x4 acc[2][8];
#pragma unroll
  for (int nt = 0; nt < 2; nt++)
#pragma unroll
    for (int vt = 0; vt < 8; vt++) acc[nt][vt] = (f32x4){0.f, 0.f, 0.f, 0.f};
  float lsum[2] = {0.f, 0.f};

  short8 kA[4], vA[8], kB[4], vB[8];
#pragma unroll
  for (int p = 0; p < 4; p++) kA[p] = *(const short8*)(Kp + p * 512);
#pragma unroll
  for (int vt = 0; vt < 8; vt++) vA[vt] = *(const short8*)(Vp + vt * 512);

  // one chunk: QK^T (hi/lo, small terms first) -> exp2 -> truncation-pack -> PV
  auto compute = [&](const short8* k, const short8* v) {
#pragma unroll
    for (int nt = 0; nt < 2; nt++) {
      f32x4 z = (f32x4){0.f, 0.f, 0.f, 0.f};
      __builtin_amdgcn_s_setprio(1);
      f32x4 s0 = __builtin_amdgcn_mfma_f32_16x16x32_bf16(k[2], qh[nt], z, 0, 0, 0);
      s0 = __builtin_amdgcn_mfma_f32_16x16x32_bf16(k[0], ql[nt], s0, 0, 0, 0);
      s0 = __builtin_amdgcn_mfma_f32_16x16x32_bf16(k[0], qh[nt], s0, 0, 0, 0);
      f32x4 s1 = __builtin_amdgcn_mfma_f32_16x16x32_bf16(k[3], qh[nt], z, 0, 0, 0);
      s1 = __builtin_amdgcn_mfma_f32_16x16x32_bf16(k[1], ql[nt], s1, 0, 0, 0);
      s1 = __builtin_amdgcn_mfma_f32_16x16x32_bf16(k[1], qh[nt], s1, 0, 0, 0);
      __builtin_amdgcn_s_setprio(0);

      float e0 = FEXP2(s0[0]), e1 = FEXP2(s0[1]), e2 = FEXP2(s0[2]), e3 = FEXP2(s0[3]);
      float e4 = FEXP2(s1[0]), e5 = FEXP2(s1[1]), e6 = FEXP2(s1[2]), e7 = FEXP2(s1[3]);
      lsum[nt] += ((e0 + e1) + (e2 + e3)) + ((e4 + e5) + (e6 + e7));
      i32x4 pi;
      pi[0] = (int)((__builtin_bit_cast(unsigned, e0) >> 16) | (__builtin_bit_cast(unsigned, e1) & 0xffff0000u));
      pi[1] = (int)((__builtin_bit_cast(unsigned, e2) >> 16) | (__builtin_bit_cast(unsigned, e3) & 0xffff0000u));
      pi[2] = (int)((__builtin_bit_cast(unsigned, e4) >> 16) | (__builtin_bit_cast(unsigned, e5) & 0xffff0000u));
      pi[3] = (int)((__builtin_bit_cast(unsigned, e6) >> 16) | (__builtin_bit_cast(unsigned, e7) & 0xffff0000u));
      short8 pp = __builtin_bit_cast(short8, pi);
      __builtin_amdgcn_s_setprio(1);
#pragma unroll
      for (int vt = 0; vt < 8; vt++)
        acc[nt][vt] = __builtin_amdgcn_mfma_f32_16x16x32_bf16(v[vt], pp, acc[nt][vt], 0, 0, 0);
      __builtin_amdgcn_s_setprio(0);
    }
  };

  for (int ci = 0; ci < 16; ci++) {
    Kp += 2048; Vp += 4096;
#pragma unroll
    for (int p = 0; p < 4; p++) kB[p] = *(const short8*)(Kp + p * 512);
#pragma unroll
    for (int vt = 0; vt < 8; vt++) vB[vt] = *(const short8*)(Vp + vt * 512);
    compute(kA, vA);

    Kp += 2048; Vp += 4096;
#pragma unroll
    for (int p = 0; p < 4; p++) kA[p] = *(const short8*)(Kp + p * 512);
#pragma unroll
    for (int vt = 0; vt < 8; vt++) vA[vt] = *(const short8*)(Vp + vt * 512);
    compute(kB, vB);
  }
  // final prefetch (chunk sp*32+32) reads one-past-range into adjacent ws regions: harmless.

  // ---- split-K tree combine: (sp2->sp0, sp3->sp1), then sp1->sp0 ----
  if (sp == 2) {
#pragma unroll
    for (int nt = 0; nt < 2; nt++) {
#pragma unroll
      for (int vt = 0; vt < 8; vt++) CombA[rg][nt * 8 + vt][lane] = acc[nt][vt];
      CombLA[rg][nt][lane] = lsum[nt];
    }
  } else if (sp == 3) {
#pragma unroll
    for (int nt = 0; nt < 2; nt++) {
#pragma unroll
      for (int vt = 0; vt < 8; vt++) CombB[rg][nt * 8 + vt][lane] = acc[nt][vt];
      CombLB[rg][nt][lane] = lsum[nt];
    }
  }
  __syncthreads();
  if (sp == 0) {
#pragma unroll
    for (int nt = 0; nt < 2; nt++) {
#pragma unroll
      for (int vt = 0; vt < 8; vt++) acc[nt][vt] += CombA[rg][nt * 8 + vt][lane];
      lsum[nt] += CombLA[rg][nt][lane];
    }
  } else if (sp == 1) {
#pragma unroll
    for (int nt = 0; nt < 2; nt++) {
#pragma unroll
      for (int vt = 0; vt < 8; vt++) acc[nt][vt] += CombB[rg][nt * 8 + vt][lane];
      lsum[nt] += CombLB[rg][nt][lane];
    }
  }
  __syncthreads();
  if (sp == 1) {
#pragma unroll
    for (int nt = 0; nt < 2; nt++) {
#pragma unroll
      for (int vt = 0; vt < 8; vt++) CombA[rg][nt * 8 + vt][lane] = acc[nt][vt];
      CombLA[rg][nt][lane] = lsum[nt];
    }
  }
  __syncthreads();
  if (sp == 0) {
#pragma unroll
    for (int nt = 0; nt < 2; nt++) {
#pragma unroll
      for (int vt = 0; vt < 8; vt++) acc[nt][vt] += CombA[rg][nt * 8 + vt][lane];
      lsum[nt] += CombLA[rg][nt][lane];
    }
#pragma unroll
    for (int nt = 0; nt < 2; nt++) {
      lsum[nt] += __shfl_xor(lsum[nt], 16);
      lsum[nt] += __shfl_xor(lsum[nt], 32);
      float rinv = 1.0f / lsum[nt];
      int nqt = rg * 2 + nt;
#pragma unroll
      for (int kc = 0; kc < 4; kc++) {
        short8 t;
#pragma unroll
        for (int r = 0; r < 4; r++) {
          t[r]     = (short)f2b(acc[nt][2 * kc][r] * rinv);
          t[r + 4] = (short)f2b(acc[nt][2 * kc + 1][r] * rinv);
        }
        *(short8*)&BC[(size_t)(nqt * 64 + lane) * 40 + kc * 8] = t;
      }
    }
  }
  __syncthreads();

  // ---- Wo GEMM + epilogue: wave w -> oc-tiles 2w, 2w+1 ----
  short8 bfr[4][4];
#pragma unroll
  for (int nqt = 0; nqt < 4; nqt++)
#pragma unroll
    for (int kc = 0; kc < 4; kc++)
      bfr[nqt][kc] = *(const short8*)&BC[(size_t)(nqt * 64 + lane) * 40 + kc * 8];

  float gamma = *gammap;
#pragma unroll
  for (int mti = 0; mti < 2; mti++) {
    int mt = wave * 2 + mti;
    short8 wf[4];
#pragma unroll
    for (int kc = 0; kc < 4; kc++)
      wf[kc] = *(const short8*)(Wof + (size_t)(mt * 4 + kc) * 512 + lane * 8);
#pragma unroll
    for (int nqt = 0; nqt < 4; nqt++) {
      f32x4 oacc = (f32x4){0.f, 0.f, 0.f, 0.f};
#pragma unroll
      for (int kc = 0; kc < 4; kc++)
        oacc = __builtin_amdgcn_mfma_f32_16x16x32_bf16(wf[kc], bfr[nqt][kc], oacc, 0, 0, 0);
#pragma unroll
      for (int r = 0; r < 4; r++) {
        int oc = mt * 16 + quad * 4 + r;
        size_t idx = ((size_t)b * CHN + oc) * NSEQ + n0 + nqt * 16 + l15;
        out[idx] = gamma * oacc[r] + x[idx];
      }
    }
  }
}

extern "C" void kernel_launch(void* const* d_in, const int* in_sizes, int n_in,
                              void* d_out, int out_size, void* d_ws, size_t ws_size,
                              hipStream_t stream) {
  const float* x  = (const float*)d_in[0];
  const float* Wt = (const float*)d_in[1];
  const float* Wp = (const float*)d_in[2];
  const float* Wg = (const float*)d_in[3];
  const float* Wo = (const float*)d_in[4];
  const float* gm = (const float*)d_in[5];
  float* out = (float*)d_out;
  u16* ws = (u16*)d_ws;
  u16* QbH  = ws + QH_OFF;
  u16* QbL  = ws + QL_OFF;
  u16* Kf   = ws + KF_OFF;
  u16* Vf   = ws + VF_OFF;
  u16* Wqkf = ws + WQKF_OFF;
  u16* Wgf  = ws + WGF_OFF;
  u16* Wof  = ws + WOF_OFF;

  prep_weights<<<80, 256, 0, stream>>>(Wt, Wp, Wg, Wo, Wqkf, Wgf, Wof);
  proj_qkv<<<1024, 256, 0, stream>>>(x, Wqkf, Wgf, QbH, QbL, Kf, Vf);
  flash_attn<<<256, 512, 0, stream>>>(QbH, QbL, Kf, Vf, Wof, x, gm, out);
}